// Round 6
// baseline (90.046 us; speedup 1.0000x reference)
//
#include <hip/hip_runtime.h>

#define B_ 4
#define N_ 512
#define D_ 768
#define A_ 128

typedef short bf16x8 __attribute__((ext_vector_type(8)));
typedef ushort u16x8 __attribute__((ext_vector_type(8)));
typedef float f32x4 __attribute__((ext_vector_type(4)));

__device__ __forceinline__ ushort f2h(float x) {  // f32 -> bf16 bits, RNE
  uint u = __builtin_bit_cast(uint, x);
  return (ushort)((u + 0x7fffu + ((u >> 16) & 1u)) >> 16);
}
__device__ __forceinline__ float h2f(ushort h) {
  uint u = ((uint)h) << 16;
  return __builtin_bit_cast(float, u);
}
__device__ __forceinline__ bf16x8 ld8(const ushort* p) {
  return *(const bf16x8*)p;
}
#define MFMA(a, b, c) __builtin_amdgcn_mfma_f32_16x16x32_bf16(a, b, c, 0, 0, 0)

// ---------------------------------------------------------------------------
// k0: fused prep.
//  blocks 0..767: split M into bf16 hi/lo, Mr [2048][768] row-major (k1 A)
//                 and Mt [4][768][512] transposed (k3 B).
//  blocks 768..863: Wt[c][k] = (c<128?W1:W2)[k][c%128] bf16 hi/lo [256][768].
// ---------------------------------------------------------------------------
__global__ __launch_bounds__(256) void k0_prep(
    const float* __restrict__ M, const float* __restrict__ W1,
    const float* __restrict__ W2, ushort* __restrict__ Mr_h,
    ushort* __restrict__ Mr_l, ushort* __restrict__ Mt_h,
    ushort* __restrict__ Mt_l, ushort* __restrict__ Wt_h,
    ushort* __restrict__ Wt_l) {
  __shared__ ushort lds_h[64][40];
  __shared__ ushort lds_l[64][40];
  const int t = threadIdx.x;
  const int bid = blockIdx.x;
  if (bid < 768) {  // ---- M part ----
    const int dq = bid % 12;
    const int rest = bid / 12;
    const int d0 = dq * 64;
    const int n0 = (rest & 15) * 32;
    const int b = rest >> 4;
    const int n = t >> 3;          // 0..31
    const int dg = (t & 7) * 8;    // 0..56
    const size_t roff = ((size_t)(b * N_ + n0 + n)) * D_ + d0 + dg;
    const float4 v0 = *(const float4*)(M + roff);
    const float4 v1 = *(const float4*)(M + roff + 4);
    const float x[8] = {v0.x, v0.y, v0.z, v0.w, v1.x, v1.y, v1.z, v1.w};
    u16x8 vh, vl;
#pragma unroll
    for (int e = 0; e < 8; ++e) {
      ushort h = f2h(x[e]);
      ushort l = f2h(x[e] - h2f(h));
      vh[e] = h;
      vl[e] = l;
      lds_h[dg + e][n] = h;
      lds_l[dg + e][n] = l;
    }
    *(u16x8*)(Mr_h + roff) = vh;
    *(u16x8*)(Mr_l + roff) = vl;
    __syncthreads();
    const int dd = t >> 2;          // 0..63
    const int ng = (t & 3) * 8;     // 0..24
    const size_t toff = ((size_t)b * D_ + d0 + dd) * N_ + n0 + ng;
    *(u16x8*)(Mt_h + toff) = *(const u16x8*)(&lds_h[dd][ng]);
    *(u16x8*)(Mt_l + toff) = *(const u16x8*)(&lds_l[dd][ng]);
  } else {  // ---- W part ----
    const int c = t;
    const int k0 = (bid - 768) * 8;
    const float* __restrict__ Wp = (c < A_) ? W1 : W2;
    const int cc = c & (A_ - 1);
    u16x8 vh, vl;
#pragma unroll
    for (int e = 0; e < 8; ++e) {
      float x = Wp[(size_t)(k0 + e) * A_ + cc];
      ushort h = f2h(x);
      vh[e] = h;
      vl[e] = f2h(x - h2f(h));
    }
    *(u16x8*)(Wt_h + (size_t)c * D_ + k0) = vh;
    *(u16x8*)(Wt_l + (size_t)c * D_ + k0) = vl;
  }
}

// ---------------------------------------------------------------------------
// k1: ws12[2048][256] = M @ [W1|W2], +bias, *2log2(e).  MFMA 16x16x32 bf16,
// 3-pass split (Ah@Bh + Ah@Bl + Al@Bh). 1 wave/block, tile 32x32, register-
// prefetch pipeline (loads for K-step k+1 issued before MFMAs of step k).
// Output row-major: w1 = cols 0..127, w2 = cols 128..255 (k2 streams rows).
// ---------------------------------------------------------------------------
__global__ __launch_bounds__(64) void k1_mfma(
    const ushort* __restrict__ Mr_h, const ushort* __restrict__ Mr_l,
    const ushort* __restrict__ Wt_h, const ushort* __restrict__ Wt_l,
    const float* __restrict__ b1, const float* __restrict__ b2,
    float* __restrict__ ws12) {
  const int l = threadIdx.x;
  const int r = l & 15, g = l >> 4;
  const int row0 = blockIdx.x * 32;
  const int cb = blockIdx.y * 32;
  const size_t oA = (size_t)(row0 + r) * D_ + g * 8;
  const size_t oA2 = oA + (size_t)16 * D_;
  const size_t oB = (size_t)(cb + r) * D_ + g * 8;
  const size_t oB2 = oB + (size_t)16 * D_;
  f32x4 acc[2][2] = {};
  bf16x8 A[2][4], Bv[2][4];
#define K1LOAD(s, k0)                                                        \
  A[s][0] = ld8(Mr_h + oA + (k0));  A[s][1] = ld8(Mr_h + oA2 + (k0));        \
  A[s][2] = ld8(Mr_l + oA + (k0));  A[s][3] = ld8(Mr_l + oA2 + (k0));        \
  Bv[s][0] = ld8(Wt_h + oB + (k0)); Bv[s][1] = ld8(Wt_h + oB2 + (k0));       \
  Bv[s][2] = ld8(Wt_l + oB + (k0)); Bv[s][3] = ld8(Wt_l + oB2 + (k0));
#define K1MM(s)                                                              \
  acc[0][0] = MFMA(A[s][0], Bv[s][0], acc[0][0]);                            \
  acc[0][0] = MFMA(A[s][0], Bv[s][2], acc[0][0]);                            \
  acc[0][0] = MFMA(A[s][2], Bv[s][0], acc[0][0]);                            \
  acc[0][1] = MFMA(A[s][0], Bv[s][1], acc[0][1]);                            \
  acc[0][1] = MFMA(A[s][0], Bv[s][3], acc[0][1]);                            \
  acc[0][1] = MFMA(A[s][2], Bv[s][1], acc[0][1]);                            \
  acc[1][0] = MFMA(A[s][1], Bv[s][0], acc[1][0]);                            \
  acc[1][0] = MFMA(A[s][1], Bv[s][2], acc[1][0]);                            \
  acc[1][0] = MFMA(A[s][3], Bv[s][0], acc[1][0]);                            \
  acc[1][1] = MFMA(A[s][1], Bv[s][1], acc[1][1]);                            \
  acc[1][1] = MFMA(A[s][1], Bv[s][3], acc[1][1]);                            \
  acc[1][1] = MFMA(A[s][3], Bv[s][1], acc[1][1]);
  K1LOAD(0, 0)
#pragma unroll
  for (int kt = 0; kt < 24; ++kt) {
    if (kt & 1) {
      if (kt + 1 < 24) { K1LOAD(0, (kt + 1) * 32) }
      K1MM(1)
    } else {
      if (kt + 1 < 24) { K1LOAD(1, (kt + 1) * 32) }
      K1MM(0)
    }
  }
#undef K1LOAD
#undef K1MM
  const float SC = 2.8853900817779268f;  // 2*log2(e): e^{2x} = 2^{SC*x}
#pragma unroll
  for (int fj = 0; fj < 2; ++fj) {
    const int c = cb + fj * 16 + r;
    const float bias = (c < A_) ? b1[c] : b2[c - A_];
#pragma unroll
    for (int fi = 0; fi < 2; ++fi)
#pragma unroll
      for (int rr = 0; rr < 4; ++rr) {
        const int row = row0 + fi * 16 + g * 4 + rr;
        ws12[(size_t)row * 256 + c] = (acc[fi][fj][rr] + bias) * SC;
      }
  }
}

// ---------------------------------------------------------------------------
// k2 v5: mask-compacted scores, STREAMING w2 access.
// 1 wave = 1 row. Compact unmasked-j list (ballot/popcount). Per chunk of 64
// compact j: each lane STREAMS its row ws12[b*512+j][128..255] contiguously
// (512B/lane, L1-resident chunk working set, 4x line reuse over c) --
// replaces v4's random gather. score = Vsum - sum_a 2v[a]*rcp(exp2(w1+w2)+1).
// Scatter to zero-init p_lds => masked exactly 0 (ref: exp(f32.min-rmax)
// underflows). exp2 only on compact entries. cnt==0 -> exact 1/512.
// ---------------------------------------------------------------------------
__global__ __launch_bounds__(256) void k2_scores(
    const float* __restrict__ ws12, const int* __restrict__ mask,
    const float* __restrict__ vw, ushort* __restrict__ ah,
    ushort* __restrict__ al) {
  __shared__ float l_w1[4][A_];
  __shared__ float l_v2[A_];
  __shared__ float p_lds[4][N_];
  __shared__ ushort jl[4][N_];
  const int t = threadIdx.x;
  const int lane = t & 63;
  const int w = t >> 6;
  const int i0 = blockIdx.x * 4;
  const int b = i0 >> 9;
  const int i = i0 + w;

  for (int k = t; k < 4 * A_; k += 256) {
    const int rr = k >> 7, c = k & 127;
    l_w1[rr][c] = ws12[(size_t)(i0 + rr) * 256 + c];
  }
  if (t < A_) l_v2[t] = -2.f * vw[t];
  for (int k = t; k < 4 * N_; k += 256) ((float*)p_lds)[k] = 0.f;
  float vs = vw[lane] + vw[64 + lane];
#pragma unroll
  for (int off = 32; off; off >>= 1) vs += __shfl_xor(vs, off);
  __syncthreads();

  // --- compaction: ascending list of unmasked j for row i ---
  int cnt = 0;
#pragma unroll
  for (int e = 0; e < 8; ++e) {
    const int m = mask[(size_t)i * N_ + e * 64 + lane];
    const unsigned long long bal = __ballot(m != 0);
    if (m) {
      const int rank = __popcll(bal & ((1ull << lane) - 1ull));
      jl[w][cnt + rank] = (ushort)(e * 64 + lane);
    }
    cnt += __popcll(bal);
  }

  const float4* __restrict__ w1q = (const float4*)&l_w1[w][0];
  const float4* __restrict__ v2q = (const float4*)&l_v2[0];
  const int np = (cnt + 63) >> 6;

  // --- pass 1: scores -> p_lds scatter, track max ---
  float smax = -3.402823466e38f;
  for (int ch = 0; ch < np; ++ch) {
    const int idx = ch * 64 + lane;
    const bool val = idx < cnt;
    const int j = jl[w][val ? idx : 0];
    const float4* __restrict__ w2q =
        (const float4*)(ws12 + ((size_t)(b * N_ + j)) * 256 + A_);
    float a0 = vs;
#pragma unroll 8
    for (int c = 0; c < 32; ++c) {
      const float4 wa = w1q[c];
      const float4 vv = v2q[c];
      const float4 x = w2q[c];
      const float e0 = __builtin_amdgcn_exp2f(wa.x + x.x);
      const float e1 = __builtin_amdgcn_exp2f(wa.y + x.y);
      const float e2 = __builtin_amdgcn_exp2f(wa.z + x.z);
      const float e3 = __builtin_amdgcn_exp2f(wa.w + x.w);
      a0 = fmaf(vv.x, __builtin_amdgcn_rcpf(e0 + 1.f), a0);
      a0 = fmaf(vv.y, __builtin_amdgcn_rcpf(e1 + 1.f), a0);
      a0 = fmaf(vv.z, __builtin_amdgcn_rcpf(e2 + 1.f), a0);
      a0 = fmaf(vv.w, __builtin_amdgcn_rcpf(e3 + 1.f), a0);
    }
    if (val) {
      p_lds[w][j] = a0;
      smax = fmaxf(smax, a0);
    }
  }
#pragma unroll
  for (int off = 32; off; off >>= 1) smax = fmaxf(smax, __shfl_xor(smax, off));

  // --- pass 2: exp on compact entries + sum ---
  const float L2E = 1.4426950408889634f;
  float psum = 0.f;
  for (int ch = 0; ch < np; ++ch) {
    const int idx = ch * 64 + lane;
    const bool val = idx < cnt;
    const int j = jl[w][val ? idx : 0];
    const float p = __builtin_amdgcn_exp2f((p_lds[w][j] - smax) * L2E);
    if (val) {
      p_lds[w][j] = p;
      psum += p;
    }
  }
#pragma unroll
  for (int off = 32; off; off >>= 1) psum += __shfl_xor(psum, off);
  const float inv = __builtin_amdgcn_rcpf(psum);

  // --- final coalesced bf16 hi/lo write ---
  u16x8 vh, vl;
  if (cnt == 0) {
#pragma unroll
    for (int e = 0; e < 8; ++e) {  // exact 1/512 (all-masked row, ref match)
      vh[e] = 0x3B00;
      vl[e] = 0;
    }
  } else {
    const float4 q0 = *(const float4*)&p_lds[w][lane * 8];
    const float4 q1 = *(const float4*)&p_lds[w][lane * 8 + 4];
    const float q[8] = {q0.x, q0.y, q0.z, q0.w, q1.x, q1.y, q1.z, q1.w};
#pragma unroll
    for (int e = 0; e < 8; ++e) {
      const float pv = q[e] * inv;
      const ushort hh = f2h(pv);
      vh[e] = hh;
      vl[e] = f2h(pv - h2f(hh));
    }
  }
  *(u16x8*)(ah + (size_t)i * N_ + lane * 8) = vh;
  *(u16x8*)(al + (size_t)i * N_ + lane * 8) = vl;
}

// ---------------------------------------------------------------------------
// k3: out[b] = attn[b] @ M[b].  MFMA 16x16x32 bf16, 3-pass split, register-
// prefetch pipeline. 1 wave/block, tile 32 i x 32 d (1536 blocks, 6 w/CU).
// ---------------------------------------------------------------------------
__global__ __launch_bounds__(64) void k3_mfma(
    const ushort* __restrict__ ah, const ushort* __restrict__ al,
    const ushort* __restrict__ Mt_h, const ushort* __restrict__ Mt_l,
    float* __restrict__ out) {
  const int l = threadIdx.x;
  const int r = l & 15, g = l >> 4;
  const int row0 = blockIdx.x * 32;    // global row b*N+i
  const int d0 = blockIdx.y * 32;
  const int b = row0 >> 9;
  const ushort* __restrict__ Bh = Mt_h + (size_t)b * D_ * N_;
  const ushort* __restrict__ Bl = Mt_l + (size_t)b * D_ * N_;
  const size_t oA = (size_t)(row0 + r) * N_ + g * 8;
  const size_t oA2 = oA + (size_t)16 * N_;
  const size_t oB = (size_t)(d0 + r) * N_ + g * 8;
  const size_t oB2 = oB + (size_t)16 * N_;
  f32x4 acc[2][2] = {};
  bf16x8 A[2][4], Bv[2][4];
#define K3LOAD(s, j0)                                                        \
  A[s][0] = ld8(ah + oA + (j0));  A[s][1] = ld8(ah + oA2 + (j0));            \
  A[s][2] = ld8(al + oA + (j0));  A[s][3] = ld8(al + oA2 + (j0));            \
  Bv[s][0] = ld8(Bh + oB + (j0)); Bv[s][1] = ld8(Bh + oB2 + (j0));           \
  Bv[s][2] = ld8(Bl + oB + (j0)); Bv[s][3] = ld8(Bl + oB2 + (j0));
#define K3MM(s)                                                              \
  acc[0][0] = MFMA(A[s][0], Bv[s][0], acc[0][0]);                            \
  acc[0][0] = MFMA(A[s][0], Bv[s][2], acc[0][0]);                            \
  acc[0][0] = MFMA(A[s][2], Bv[s][0], acc[0][0]);                            \
  acc[0][1] = MFMA(A[s][0], Bv[s][1], acc[0][1]);                            \
  acc[0][1] = MFMA(A[s][0], Bv[s][3], acc[0][1]);                            \
  acc[0][1] = MFMA(A[s][2], Bv[s][1], acc[0][1]);                            \
  acc[1][0] = MFMA(A[s][1], Bv[s][0], acc[1][0]);                            \
  acc[1][0] = MFMA(A[s][1], Bv[s][2], acc[1][0]);                            \
  acc[1][0] = MFMA(A[s][3], Bv[s][0], acc[1][0]);                            \
  acc[1][1] = MFMA(A[s][1], Bv[s][1], acc[1][1]);                            \
  acc[1][1] = MFMA(A[s][1], Bv[s][3], acc[1][1]);                            \
  acc[1][1] = MFMA(A[s][3], Bv[s][1], acc[1][1]);
  K3LOAD(0, 0)
#pragma unroll
  for (int kt = 0; kt < 16; ++kt) {
    if (kt & 1) {
      if (kt + 1 < 16) { K3LOAD(0, (kt + 1) * 32) }
      K3MM(1)
    } else {
      if (kt + 1 < 16) { K3LOAD(1, (kt + 1) * 32) }
      K3MM(0)
    }
  }
#undef K3LOAD
#undef K3MM
#pragma unroll
  for (int fi = 0; fi < 2; ++fi)
#pragma unroll
    for (int fd = 0; fd < 2; ++fd)
#pragma unroll
      for (int rr = 0; rr < 4; ++rr)
        out[(size_t)(row0 + fi * 16 + g * 4 + rr) * D_ + d0 + fd * 16 + r] =
            acc[fi][fd][rr];
}

extern "C" void kernel_launch(void* const* d_in, const int* in_sizes, int n_in,
                              void* d_out, int out_size, void* d_ws,
                              size_t ws_size, hipStream_t stream) {
  const float* M = (const float*)d_in[0];
  const int* mask = (const int*)d_in[1];
  const float* W1 = (const float*)d_in[2];
  const float* b1 = (const float*)d_in[3];
  const float* W2 = (const float*)d_in[4];
  const float* b2 = (const float*)d_in[5];
  const float* vw = (const float*)d_in[6];
  float* out = (float*)d_out;

  // workspace carve-up: 18.75 MB total
  float* ws12 = (float*)d_ws;                     // [2048][256] f32   2 MB
  ushort* ah = (ushort*)(ws12 + 2048 * 256);      // [2048][512] bf16  2 MB
  ushort* al = ah + 2048 * N_;                    //                   2 MB
  ushort* Mr_h = al + 2048 * N_;                  // [2048][768] bf16  3 MB
  ushort* Mr_l = Mr_h + 2048 * D_;                //                   3 MB
  ushort* Mt_h = Mr_l + 2048 * D_;                // [4][768][512]     3 MB
  ushort* Mt_l = Mt_h + 2048 * D_;                //                   3 MB
  ushort* Wt_h = Mt_l + 2048 * D_;                // [256][768] bf16   .375
  ushort* Wt_l = Wt_h + 256 * D_;                 //                   .375

  k0_prep<<<864, 256, 0, stream>>>(M, W1, W2, Mr_h, Mr_l, Mt_h, Mt_l,
                                   Wt_h, Wt_l);
  k1_mfma<<<dim3(2048 / 32, 8), 64, 0, stream>>>(Mr_h, Mr_l, Wt_h, Wt_l,
                                                 b1, b2, ws12);
  k2_scores<<<(B_ * N_) / 4, 256, 0, stream>>>(ws12, mask, vw, ah, al);
  k3_mfma<<<dim3(2048 / 32, D_ / 32), 64, 0, stream>>>(ah, al, Mt_h, Mt_l, out);
}

// Round 7
// 85.412 us; speedup vs baseline: 1.0543x; 1.0543x over previous
//
#include <hip/hip_runtime.h>

#define B_ 4
#define N_ 512
#define D_ 768
#define A_ 128

typedef short bf16x8 __attribute__((ext_vector_type(8)));
typedef ushort u16x8 __attribute__((ext_vector_type(8)));
typedef float f32x4 __attribute__((ext_vector_type(4)));

__device__ __forceinline__ ushort f2h(float x) {  // f32 -> bf16 bits, RNE
  uint u = __builtin_bit_cast(uint, x);
  return (ushort)((u + 0x7fffu + ((u >> 16) & 1u)) >> 16);
}
__device__ __forceinline__ float h2f(ushort h) {
  uint u = ((uint)h) << 16;
  return __builtin_bit_cast(float, u);
}
__device__ __forceinline__ bf16x8 ld8(const ushort* p) {
  return *(const bf16x8*)p;
}
#define MFMA(a, b, c) __builtin_amdgcn_mfma_f32_16x16x32_bf16(a, b, c, 0, 0, 0)

// ---------------------------------------------------------------------------
// k0: fused prep.
//  blocks 0..767: split M into bf16 hi/lo, Mr [2048][768] row-major (k1 A)
//                 and Mt [4][768][512] transposed (k3 B).
//  blocks 768..863: Wt[c][k] = (c<128?W1:W2)[k][c%128] bf16 hi/lo [256][768].
// ---------------------------------------------------------------------------
__global__ __launch_bounds__(256) void k0_prep(
    const float* __restrict__ M, const float* __restrict__ W1,
    const float* __restrict__ W2, ushort* __restrict__ Mr_h,
    ushort* __restrict__ Mr_l, ushort* __restrict__ Mt_h,
    ushort* __restrict__ Mt_l, ushort* __restrict__ Wt_h,
    ushort* __restrict__ Wt_l) {
  __shared__ ushort lds_h[64][40];
  __shared__ ushort lds_l[64][40];
  const int t = threadIdx.x;
  const int bid = blockIdx.x;
  if (bid < 768) {  // ---- M part ----
    const int dq = bid % 12;
    const int rest = bid / 12;
    const int d0 = dq * 64;
    const int n0 = (rest & 15) * 32;
    const int b = rest >> 4;
    const int n = t >> 3;          // 0..31
    const int dg = (t & 7) * 8;    // 0..56
    const size_t roff = ((size_t)(b * N_ + n0 + n)) * D_ + d0 + dg;
    const float4 v0 = *(const float4*)(M + roff);
    const float4 v1 = *(const float4*)(M + roff + 4);
    const float x[8] = {v0.x, v0.y, v0.z, v0.w, v1.x, v1.y, v1.z, v1.w};
    u16x8 vh, vl;
#pragma unroll
    for (int e = 0; e < 8; ++e) {
      ushort h = f2h(x[e]);
      ushort l = f2h(x[e] - h2f(h));
      vh[e] = h;
      vl[e] = l;
      lds_h[dg + e][n] = h;
      lds_l[dg + e][n] = l;
    }
    *(u16x8*)(Mr_h + roff) = vh;
    *(u16x8*)(Mr_l + roff) = vl;
    __syncthreads();
    const int dd = t >> 2;          // 0..63
    const int ng = (t & 3) * 8;     // 0..24
    const size_t toff = ((size_t)b * D_ + d0 + dd) * N_ + n0 + ng;
    *(u16x8*)(Mt_h + toff) = *(const u16x8*)(&lds_h[dd][ng]);
    *(u16x8*)(Mt_l + toff) = *(const u16x8*)(&lds_l[dd][ng]);
  } else {  // ---- W part ----
    const int c = t;
    const int k0 = (bid - 768) * 8;
    const float* __restrict__ Wp = (c < A_) ? W1 : W2;
    const int cc = c & (A_ - 1);
    u16x8 vh, vl;
#pragma unroll
    for (int e = 0; e < 8; ++e) {
      float x = Wp[(size_t)(k0 + e) * A_ + cc];
      ushort h = f2h(x);
      vh[e] = h;
      vl[e] = f2h(x - h2f(h));
    }
    *(u16x8*)(Wt_h + (size_t)c * D_ + k0) = vh;
    *(u16x8*)(Wt_l + (size_t)c * D_ + k0) = vl;
  }
}

// ---------------------------------------------------------------------------
// k1: ws12[2048][256] = M @ [W1|W2], +bias, *2log2(e).  MFMA 16x16x32 bf16,
// 3-pass split (Ah@Bh + Ah@Bl + Al@Bh). 1 wave/block, tile 32x32, register-
// prefetch pipeline. w1 = cols 0..127, w2 = cols 128..255.
// ---------------------------------------------------------------------------
__global__ __launch_bounds__(64) void k1_mfma(
    const ushort* __restrict__ Mr_h, const ushort* __restrict__ Mr_l,
    const ushort* __restrict__ Wt_h, const ushort* __restrict__ Wt_l,
    const float* __restrict__ b1, const float* __restrict__ b2,
    float* __restrict__ ws12) {
  const int l = threadIdx.x;
  const int r = l & 15, g = l >> 4;
  const int row0 = blockIdx.x * 32;
  const int cb = blockIdx.y * 32;
  const size_t oA = (size_t)(row0 + r) * D_ + g * 8;
  const size_t oA2 = oA + (size_t)16 * D_;
  const size_t oB = (size_t)(cb + r) * D_ + g * 8;
  const size_t oB2 = oB + (size_t)16 * D_;
  f32x4 acc[2][2] = {};
  bf16x8 A[2][4], Bv[2][4];
#define K1LOAD(s, k0)                                                        \
  A[s][0] = ld8(Mr_h + oA + (k0));  A[s][1] = ld8(Mr_h + oA2 + (k0));        \
  A[s][2] = ld8(Mr_l + oA + (k0));  A[s][3] = ld8(Mr_l + oA2 + (k0));        \
  Bv[s][0] = ld8(Wt_h + oB + (k0)); Bv[s][1] = ld8(Wt_h + oB2 + (k0));       \
  Bv[s][2] = ld8(Wt_l + oB + (k0)); Bv[s][3] = ld8(Wt_l + oB2 + (k0));
#define K1MM(s)                                                              \
  acc[0][0] = MFMA(A[s][0], Bv[s][0], acc[0][0]);                            \
  acc[0][0] = MFMA(A[s][0], Bv[s][2], acc[0][0]);                            \
  acc[0][0] = MFMA(A[s][2], Bv[s][0], acc[0][0]);                            \
  acc[0][1] = MFMA(A[s][0], Bv[s][1], acc[0][1]);                            \
  acc[0][1] = MFMA(A[s][0], Bv[s][3], acc[0][1]);                            \
  acc[0][1] = MFMA(A[s][2], Bv[s][1], acc[0][1]);                            \
  acc[1][0] = MFMA(A[s][1], Bv[s][0], acc[1][0]);                            \
  acc[1][0] = MFMA(A[s][1], Bv[s][2], acc[1][0]);                            \
  acc[1][0] = MFMA(A[s][3], Bv[s][0], acc[1][0]);                            \
  acc[1][1] = MFMA(A[s][1], Bv[s][1], acc[1][1]);                            \
  acc[1][1] = MFMA(A[s][1], Bv[s][3], acc[1][1]);                            \
  acc[1][1] = MFMA(A[s][3], Bv[s][1], acc[1][1]);
  K1LOAD(0, 0)
#pragma unroll
  for (int kt = 0; kt < 24; ++kt) {
    if (kt & 1) {
      if (kt + 1 < 24) { K1LOAD(0, (kt + 1) * 32) }
      K1MM(1)
    } else {
      if (kt + 1 < 24) { K1LOAD(1, (kt + 1) * 32) }
      K1MM(0)
    }
  }
#undef K1LOAD
#undef K1MM
  const float SC = 2.8853900817779268f;  // 2*log2(e): e^{2x} = 2^{SC*x}
#pragma unroll
  for (int fj = 0; fj < 2; ++fj) {
    const int c = cb + fj * 16 + r;
    const float bias = (c < A_) ? b1[c] : b2[c - A_];
#pragma unroll
    for (int fi = 0; fi < 2; ++fi)
#pragma unroll
      for (int rr = 0; rr < 4; ++rr) {
        const int row = row0 + fi * 16 + g * 4 + rr;
        ws12[(size_t)row * 256 + c] = (acc[fi][fj][rr] + bias) * SC;
      }
  }
}

// ---------------------------------------------------------------------------
// k2 v6: mask-compacted scores with lane = a-dim (coalesced w2 reads).
// Block = 4 waves, wave = row. Per compact j: 64 lanes read ONE w2 row
// (float2/lane, 512B coalesced), compute 2 tanh-core elems, write partial to
// wave-private red[jj][65]; after 64 j's, transpose-reduce (lane=jj, pad-65
// conflict-free) -> per-lane compact scores in s_reg[8] (static idx).
// Softmax: masked entries exactly 0 (ref underflow), cnt==0 -> exact 1/512.
// Output: bf16 hi/lo split for k3.
// ---------------------------------------------------------------------------
__global__ __launch_bounds__(256) void k2_scores(
    const float* __restrict__ ws12, const int* __restrict__ mask,
    const float* __restrict__ vw, ushort* __restrict__ ah,
    ushort* __restrict__ al) {
  __shared__ float red[4][64][65];   // 66.6 KB, wave-private slices
  __shared__ float p_lds[4][N_];     // 8 KB
  __shared__ ushort jl[4][N_];       // 4 KB
  const int t = threadIdx.x;
  const int lane = t & 63;
  const int w = t >> 6;
  const int i0 = blockIdx.x * 4;
  const int b = i0 >> 9;
  const int i = i0 + w;

  // lane = a-pair: w1/v in registers
  const float2 w1v = *(const float2*)(ws12 + (size_t)i * 256 + lane * 2);
  const float2 vv = *(const float2*)(vw + lane * 2);
  const float v2a = -2.f * vv.x;
  const float v2b = -2.f * vv.y;
  float vs = vv.x + vv.y;  // -> sum over all a via butterfly
#pragma unroll
  for (int off = 32; off; off >>= 1) vs += __shfl_xor(vs, off);

  for (int k = t; k < 4 * N_; k += 256) ((float*)p_lds)[k] = 0.f;

  // compaction: ascending list of unmasked j for row i (wave-private)
  int cnt = 0;
#pragma unroll
  for (int e = 0; e < 8; ++e) {
    const int m = mask[(size_t)i * N_ + e * 64 + lane];
    const unsigned long long bal = __ballot(m != 0);
    if (m) {
      const int rank = __popcll(bal & ((1ull << lane) - 1ull));
      jl[w][cnt + rank] = (ushort)(e * 64 + lane);
    }
    cnt += __popcll(bal);
  }
  __syncthreads();  // p_lds zero visible to all (jl/red are wave-private)

  const float* __restrict__ w2base = ws12 + (size_t)b * N_ * 256 + A_;
  float s_reg[8];
  float rmax = -3.402823466e38f;

#pragma unroll
  for (int ch = 0; ch < 8; ++ch) {
    if (ch * 64 < cnt) {
      // compute phase: lane = a-pair, iterate 64 (compact) j's
#pragma unroll 8
      for (int jj = 0; jj < 64; ++jj) {
        const int idx = ch * 64 + jj;
        const int jr = jl[w][idx < cnt ? idx : 0];  // broadcast read
        const float2 x = *(const float2*)(w2base + (size_t)jr * 256 + lane * 2);
        const float e0 = __builtin_amdgcn_exp2f(w1v.x + x.x);
        const float e1 = __builtin_amdgcn_exp2f(w1v.y + x.y);
        red[w][jj][lane] = fmaf(v2a, __builtin_amdgcn_rcpf(e0 + 1.f),
                                v2b * __builtin_amdgcn_rcpf(e1 + 1.f));
      }
      // transpose-reduce: lane = jj (stride-65 rows: conflict-free b32)
      float s = vs;
#pragma unroll 16
      for (int k = 0; k < 64; ++k) s += red[w][lane][k];
      const int myidx = ch * 64 + lane;
      s_reg[ch] = s;
      if (myidx < cnt) rmax = fmaxf(rmax, s);
    }
  }
#pragma unroll
  for (int off = 32; off; off >>= 1) rmax = fmaxf(rmax, __shfl_xor(rmax, off));

  const float L2E = 1.4426950408889634f;
  float psum = 0.f;
#pragma unroll
  for (int ch = 0; ch < 8; ++ch) {
    if (ch * 64 < cnt) {
      const int myidx = ch * 64 + lane;
      if (myidx < cnt) {
        const float p = __builtin_amdgcn_exp2f((s_reg[ch] - rmax) * L2E);
        psum += p;
        p_lds[w][jl[w][myidx]] = p;  // scatter once per compact j
      }
    }
  }
#pragma unroll
  for (int off = 32; off; off >>= 1) psum += __shfl_xor(psum, off);
  const float inv = __builtin_amdgcn_rcpf(psum);

  // final coalesced bf16 hi/lo write
  u16x8 vh, vl;
  if (cnt == 0) {
#pragma unroll
    for (int e = 0; e < 8; ++e) {  // exact 1/512 (all-masked row, ref match)
      vh[e] = 0x3B00;
      vl[e] = 0;
    }
  } else {
    const float4 q0 = *(const float4*)&p_lds[w][lane * 8];
    const float4 q1 = *(const float4*)&p_lds[w][lane * 8 + 4];
    const float q[8] = {q0.x, q0.y, q0.z, q0.w, q1.x, q1.y, q1.z, q1.w};
#pragma unroll
    for (int e = 0; e < 8; ++e) {
      const float pv = q[e] * inv;
      const ushort hh = f2h(pv);
      vh[e] = hh;
      vl[e] = f2h(pv - h2f(hh));
    }
  }
  *(u16x8*)(ah + (size_t)i * N_ + lane * 8) = vh;
  *(u16x8*)(al + (size_t)i * N_ + lane * 8) = vl;
}

// ---------------------------------------------------------------------------
// k3: out[b] = attn[b] @ M[b].  MFMA 16x16x32 bf16, 3-pass split, register-
// prefetch pipeline. 1 wave/block, tile 32 i x 32 d (1536 blocks, 6 w/CU).
// ---------------------------------------------------------------------------
__global__ __launch_bounds__(64) void k3_mfma(
    const ushort* __restrict__ ah, const ushort* __restrict__ al,
    const ushort* __restrict__ Mt_h, const ushort* __restrict__ Mt_l,
    float* __restrict__ out) {
  const int l = threadIdx.x;
  const int r = l & 15, g = l >> 4;
  const int row0 = blockIdx.x * 32;    // global row b*N+i
  const int d0 = blockIdx.y * 32;
  const int b = row0 >> 9;
  const ushort* __restrict__ Bh = Mt_h + (size_t)b * D_ * N_;
  const ushort* __restrict__ Bl = Mt_l + (size_t)b * D_ * N_;
  const size_t oA = (size_t)(row0 + r) * N_ + g * 8;
  const size_t oA2 = oA + (size_t)16 * N_;
  const size_t oB = (size_t)(d0 + r) * N_ + g * 8;
  const size_t oB2 = oB + (size_t)16 * N_;
  f32x4 acc[2][2] = {};
  bf16x8 A[2][4], Bv[2][4];
#define K3LOAD(s, j0)                                                        \
  A[s][0] = ld8(ah + oA + (j0));  A[s][1] = ld8(ah + oA2 + (j0));            \
  A[s][2] = ld8(al + oA + (j0));  A[s][3] = ld8(al + oA2 + (j0));            \
  Bv[s][0] = ld8(Bh + oB + (j0)); Bv[s][1] = ld8(Bh + oB2 + (j0));           \
  Bv[s][2] = ld8(Bl + oB + (j0)); Bv[s][3] = ld8(Bl + oB2 + (j0));
#define K3MM(s)                                                              \
  acc[0][0] = MFMA(A[s][0], Bv[s][0], acc[0][0]);                            \
  acc[0][0] = MFMA(A[s][0], Bv[s][2], acc[0][0]);                            \
  acc[0][0] = MFMA(A[s][2], Bv[s][0], acc[0][0]);                            \
  acc[0][1] = MFMA(A[s][0], Bv[s][1], acc[0][1]);                            \
  acc[0][1] = MFMA(A[s][0], Bv[s][3], acc[0][1]);                            \
  acc[0][1] = MFMA(A[s][2], Bv[s][1], acc[0][1]);                            \
  acc[1][0] = MFMA(A[s][1], Bv[s][0], acc[1][0]);                            \
  acc[1][0] = MFMA(A[s][1], Bv[s][2], acc[1][0]);                            \
  acc[1][0] = MFMA(A[s][3], Bv[s][0], acc[1][0]);                            \
  acc[1][1] = MFMA(A[s][1], Bv[s][1], acc[1][1]);                            \
  acc[1][1] = MFMA(A[s][1], Bv[s][3], acc[1][1]);                            \
  acc[1][1] = MFMA(A[s][3], Bv[s][1], acc[1][1]);
  K3LOAD(0, 0)
#pragma unroll
  for (int kt = 0; kt < 16; ++kt) {
    if (kt & 1) {
      if (kt + 1 < 16) { K3LOAD(0, (kt + 1) * 32) }
      K3MM(1)
    } else {
      if (kt + 1 < 16) { K3LOAD(1, (kt + 1) * 32) }
      K3MM(0)
    }
  }
#undef K3LOAD
#undef K3MM
#pragma unroll
  for (int fi = 0; fi < 2; ++fi)
#pragma unroll
    for (int fd = 0; fd < 2; ++fd)
#pragma unroll
      for (int rr = 0; rr < 4; ++rr)
        out[(size_t)(row0 + fi * 16 + g * 4 + rr) * D_ + d0 + fd * 16 + r] =
            acc[fi][fd][rr];
}

extern "C" void kernel_launch(void* const* d_in, const int* in_sizes, int n_in,
                              void* d_out, int out_size, void* d_ws,
                              size_t ws_size, hipStream_t stream) {
  const float* M = (const float*)d_in[0];
  const int* mask = (const int*)d_in[1];
  const float* W1 = (const float*)d_in[2];
  const float* b1 = (const float*)d_in[3];
  const float* W2 = (const float*)d_in[4];
  const float* b2 = (const float*)d_in[5];
  const float* vw = (const float*)d_in[6];
  float* out = (float*)d_out;

  // workspace carve-up: 18.75 MB total
  float* ws12 = (float*)d_ws;                     // [2048][256] f32   2 MB
  ushort* ah = (ushort*)(ws12 + 2048 * 256);      // [2048][512] bf16  2 MB
  ushort* al = ah + 2048 * N_;                    //                   2 MB
  ushort* Mr_h = al + 2048 * N_;                  // [2048][768] bf16  3 MB
  ushort* Mr_l = Mr_h + 2048 * D_;                //                   3 MB
  ushort* Mt_h = Mr_l + 2048 * D_;                // [4][768][512]     3 MB
  ushort* Mt_l = Mt_h + 2048 * D_;                //                   3 MB
  ushort* Wt_h = Mt_l + 2048 * D_;                // [256][768] bf16   .375
  ushort* Wt_l = Wt_h + 256 * D_;                 //                   .375

  k0_prep<<<864, 256, 0, stream>>>(M, W1, W2, Mr_h, Mr_l, Mt_h, Mt_l,
                                   Wt_h, Wt_l);
  k1_mfma<<<dim3(2048 / 32, 8), 64, 0, stream>>>(Mr_h, Mr_l, Wt_h, Wt_l,
                                                 b1, b2, ws12);
  k2_scores<<<(B_ * N_) / 4, 256, 0, stream>>>(ws12, mask, vw, ah, al);
  k3_mfma<<<dim3(2048 / 32, D_ / 32), 64, 0, stream>>>(ah, al, Mt_h, Mt_l, out);
}